// Round 5
// baseline (467.643 us; speedup 1.0000x reference)
//
#include <hip/hip_runtime.h>
#include <hip/hip_fp16.h>

#define NN   512
#define TT   128
#define DD   128
#define NC   64     // rows per chunk
#define NCHUNK 8
#define SRH  136    // f16 tile row stride (halfs): 272 B rows, 16B-aligned
#define WR   68     // wTt row stride (floats): rows 16B-aligned (272B)

// Precompute per-head projected attention vectors (all fp32):
//   v_h[d] = sum_j W1[d][16h+j]*Wdst[j],  u_h[d] = sum_j W1[d][16h+j]*Wsrc[j]
//   ec[h]  = ba + sum_j b1[16h+j]*(Wsrc[j]+Wdst[j])
// ws layout: [0..1023] vtab[(h>>1)*256 + (d>>2)*8 + (h&1)*4 + (d&3)]
//            [2048..3071] utab[d*8+h] ; [3072..3079] ec[h]
__global__ void gat_prep(const float* __restrict__ W1, const float* __restrict__ b1,
                         const float* __restrict__ Wa, const float* __restrict__ ba,
                         float* __restrict__ ws)
{
  int idx = blockIdx.x*256 + threadIdx.x;   // 0..1023
  int d = idx >> 3, h = idx & 7;
  float v = 0.f, u = 0.f;
  for (int j = 0; j < 16; ++j){
    float w1 = W1[d*DD + h*16 + j];
    v += w1 * Wa[16 + j];
    u += w1 * Wa[j];
  }
  ws[(h>>1)*256 + (d>>2)*8 + (h&1)*4 + (d&3)] = v;
  ws[2048 + d*8 + h] = u;
  if (idx < 8){
    float ec = ba[0];
    for (int j = 0; j < 16; ++j)
      ec += b1[idx*16 + j] * (Wa[j] + Wa[16 + j]);
    ws[3072 + idx] = ec;
  }
}

static __device__ __forceinline__ float2 up2(unsigned u){
  union { unsigned u; __half2 h; } c; c.u = u;
  return __half22float2(c.h);
}
static __device__ __forceinline__ unsigned pk2(float x, float y){
  union { __half2 h; unsigned u; } c;
  c.h = __float22half2_rn(make_float2(x, y));
  return c.u;
}
static __device__ __forceinline__ void st8(ushort* p, float4 a, float4 b){
  uint4 u;
  u.x = pk2(a.x, a.y); u.y = pk2(a.z, a.w);
  u.z = pk2(b.x, b.y); u.w = pk2(b.z, b.w);
  *(uint4*)p = u;
}

// One block per (b,t). Flash-style online softmax, 8 chunks of 64 rows.
// f16 LDS tile, double-buffered: chunk c lives in tile[c&1]; the prefetched
// chunk c+1 is converted+stored into the other buffer at the TOP of chunk c
// (its readers finished at the previous barrier) => ONE barrier per chunk,
// staging fully overlapped with compute. Wave w owns heads {2w,2w+1}; score
// lane = row (v-table via uniform s_loads); agg lane = (octet o=l&15, rowgrp
// q=l>>4), 16-lane groups read contiguous 256B => conflict-free b128.
__global__ __launch_bounds__(256, 4) void gat_main(
    const float* __restrict__ hin, const float* __restrict__ adj, const float* __restrict__ mask,
    const float* __restrict__ W1,  const float* __restrict__ b1,
    const float* __restrict__ W2,  const float* __restrict__ b2,
    const float* __restrict__ ws,  float* __restrict__ out)
{
  __shared__ __align__(16) ushort tile0[NC*SRH];   // 17408 B
  __shared__ __align__(16) ushort tile1[NC*SRH];   // 17408 B
  __shared__ __align__(16) float wTt[8*WR];        // 2176 B
  __shared__ float Karr[8], RL[8];
  __shared__ float targ[128];

  // epilogue-only f32 buffers aliased onto tile0 (dead after chunk loop)
  float* const aggfin = (float*)tile0;            // 8*132 = 1056 floats
  float* const catbuf = (float*)tile0 + 1056;     // 256
  float* const oppart = (float*)tile0 + 1312;     // 256

  const int t    = threadIdx.x;
  const int bb   = blockIdx.x >> 7;
  const int tt   = blockIdx.x & 127;
  const int wave = t >> 6;
  const int lane = t & 63;
  const int h0   = 2*wave;

  // wave-uniform v-table pointer -> scalar s_loads (off the DS pipe)
  const int wv = __builtin_amdgcn_readfirstlane(wave);
  const float4* __restrict__ vg = (const float4*)(ws + (wv << 8));

  const int o = lane & 15;   // agg: col-octet (8 floats)
  const int q = lane >> 4;   // agg: row-group (16 rows)

  float mrun0 = -1e30f, mrun1 = -1e30f;
  float Zp0 = 0.f, Zp1 = 0.f, SWp0 = 0.f, SWp1 = 0.f;
  float4 aA0 = {0,0,0,0}, aA1 = {0,0,0,0};   // head h0, cols 8o..8o+7
  float4 aB0 = {0,0,0,0}, aB1 = {0,0,0,0};   // head h0+1

  // staging map: thread = (rw = t>>4 row-within-16, co = t&15 col-octet)
  const int rw = t >> 4, co = t & 15;
  const float4* __restrict__ hg4 = (const float4*)hin;
  const long dI4 = 16L*TT*(DD/4);            // 16-row step in float4s
  const long dC4 = (long)NC*TT*(DD/4);       // chunk step
  const long g0f4 = ((long)(bb*NN + rw)*TT + tt)*(DD/4) + 2*co;

  float4 pfa0, pfb0, pfa1, pfb1, pfa2, pfb2, pfa3, pfb3;  // named: never scratch

#define PF_LOAD(C) do{ const long _g = g0f4 + (long)(C)*dC4; \
    pfa0 = hg4[_g];          pfb0 = hg4[_g + 1]; \
    pfa1 = hg4[_g +   dI4];  pfb1 = hg4[_g +   dI4 + 1]; \
    pfa2 = hg4[_g + 2*dI4];  pfb2 = hg4[_g + 2*dI4 + 1]; \
    pfa3 = hg4[_g + 3*dI4];  pfb3 = hg4[_g + 3*dI4 + 1]; }while(0)
#define PF_STORE(TB) do{ \
    st8(&(TB)[(rw +  0)*SRH + 8*co], pfa0, pfb0); \
    st8(&(TB)[(rw + 16)*SRH + 8*co], pfa1, pfb1); \
    st8(&(TB)[(rw + 32)*SRH + 8*co], pfa2, pfb2); \
    st8(&(TB)[(rw + 48)*SRH + 8*co], pfa3, pfb3); }while(0)

  // ---- prologue: chunk 0 -> tile0; prefetch chunk 1; mask/adj for chunk 0 ----
  PF_LOAD(0);
  float mvc = mask[(long)(bb*NN + lane)*TT + tt];
  float avc = adj[(long)(bb*TT + tt)*NN + lane];
  PF_STORE(tile0);
  PF_LOAD(1);
  __syncthreads();

  // row n=0 (tile0 row 0, f16): target_h and score constant K_h
  if (t < 128){
    float a = b1[t];
    for (int d = 0; d < 128; ++d)
      a += __half2float(((const __half*)tile0)[d]) * W1[d*DD + t];
    targ[t] = a;
  } else if (t < 136){
    int h8 = t - 128;
    float a = ws[3072 + h8];
    for (int d = 0; d < 128; ++d)
      a += __half2float(((const __half*)tile0)[d]) * ws[2048 + d*8 + h8];
    Karr[h8] = a;
  }
  __syncthreads();

  const float K0 = Karr[h0], K1 = Karr[h0 + 1];

  for (int c = 0; c < NCHUNK; ++c){
    ushort* tb = (c & 1) ? tile1 : tile0;     // current chunk
    ushort* to = (c & 1) ? tile0 : tile1;     // destination for chunk c+1

    // store prefetched chunk c+1 (readers of `to` finished at prev barrier)
    if (c < NCHUNK-1) PF_STORE(to);
    // issue chunk c+2 loads: a full chunk of compute hides their latency
    if (c < NCHUNK-2) PF_LOAD(c+2);
    // prefetch next chunk's mask/adj
    float mvn = 0.f, avn = 0.f;
    if (c < NCHUNK-1){
      mvn = mask[(long)(bb*NN + (c+1)*NC + lane)*TT + tt];
      avn = adj[(long)(bb*TT + tt)*NN + (c+1)*NC + lane];
    }

    // ---- scores: s_h(row=lane) = K_h + h_row . v_h ----
    float s0 = K0, s1 = K1;
    {
      const ushort* rowp = &tb[lane*SRH];
      #pragma unroll 4
      for (int j = 0; j < 16; ++j){
        uint4 u = *(const uint4*)&rowp[8*j];
        float2 p0 = up2(u.x), p1 = up2(u.y), p2 = up2(u.z), p3 = up2(u.w);
        float4 va0 = vg[4*j], vb0 = vg[4*j+1], va1 = vg[4*j+2], vb1 = vg[4*j+3];
        s0 += p0.x*va0.x + p0.y*va0.y + p1.x*va0.z + p1.y*va0.w
            + p2.x*va1.x + p2.y*va1.y + p3.x*va1.z + p3.y*va1.w;
        s1 += p0.x*vb0.x + p0.y*vb0.y + p1.x*vb0.z + p1.y*vb0.w
            + p2.x*vb1.x + p2.y*vb1.y + p3.x*vb1.z + p3.y*vb1.w;
      }
    }
    const float inva = (avc == 0.f) ? 1e-9f : (1.f/avc);

    float sm0 = (mvc > 0.f) ? s0 : -1e30f;
    float sm1 = (mvc > 0.f) ? s1 : -1e30f;
    #pragma unroll
    for (int off = 32; off >= 1; off >>= 1){
      sm0 = fmaxf(sm0, __shfl_xor(sm0, off));
      sm1 = fmaxf(sm1, __shfl_xor(sm1, off));
    }
    float mn0 = fmaxf(mrun0, sm0), mn1 = fmaxf(mrun1, sm1);
    float sc0 = __expf(mrun0 - mn0), sc1 = __expf(mrun1 - mn1);
    mrun0 = mn0; mrun1 = mn1;

    float e0 = (mvc > 0.f) ? __expf(s0 - mn0) : 0.f;
    float e1 = (mvc > 0.f) ? __expf(s1 - mn1) : 0.f;
    float w0 = e0*inva, w1 = e1*inva;
    wTt[h0*WR + lane]       = w0;
    wTt[(h0 + 1)*WR + lane] = w1;
    Zp0  = Zp0*sc0  + e0;  Zp1  = Zp1*sc1  + e1;
    SWp0 = SWp0*sc0 + w0;  SWp1 = SWp1*sc1 + w1;

    // ---- agg (wave-local wTt rows => no barrier needed) ----
    {
      aA0.x*=sc0; aA0.y*=sc0; aA0.z*=sc0; aA0.w*=sc0;
      aA1.x*=sc0; aA1.y*=sc0; aA1.z*=sc0; aA1.w*=sc0;
      aB0.x*=sc1; aB0.y*=sc1; aB0.z*=sc1; aB0.w*=sc1;
      aB1.x*=sc1; aB1.y*=sc1; aB1.z*=sc1; aB1.w*=sc1;
#define AGGROW(R, WA, WB) { \
      uint4 u = *(const uint4*)&tb[(R)*SRH + 8*o]; \
      float2 p0 = up2(u.x), p1 = up2(u.y), p2 = up2(u.z), p3 = up2(u.w); \
      aA0.x += (WA)*p0.x; aA0.y += (WA)*p0.y; aA0.z += (WA)*p1.x; aA0.w += (WA)*p1.y; \
      aA1.x += (WA)*p2.x; aA1.y += (WA)*p2.y; aA1.z += (WA)*p3.x; aA1.w += (WA)*p3.y; \
      aB0.x += (WB)*p0.x; aB0.y += (WB)*p0.y; aB0.z += (WB)*p1.x; aB0.w += (WB)*p1.y; \
      aB1.x += (WB)*p2.x; aB1.y += (WB)*p2.y; aB1.z += (WB)*p3.x; aB1.w += (WB)*p3.y; }
      #pragma unroll
      for (int k = 0; k < 4; ++k){
        float4 wA = *(const float4*)&wTt[h0*WR + 16*q + 4*k];
        float4 wB = *(const float4*)&wTt[(h0+1)*WR + 16*q + 4*k];
        const int rb = 16*q + 4*k;
        AGGROW(rb+0, wA.x, wB.x);
        AGGROW(rb+1, wA.y, wB.y);
        AGGROW(rb+2, wA.z, wB.z);
        AGGROW(rb+3, wA.w, wB.w);
      }
    }
    __syncthreads();   // chunk done: tb reads finished, `to` stores visible
    mvc = mvn; avc = avn;
  }

  // ---- epilogue ----
  // combine 4 row-groups (lanes differing in bits 4,5) for all 16 acc comps
#define R2X(v) { v += __shfl_xor(v, 16); v += __shfl_xor(v, 32); }
  R2X(aA0.x) R2X(aA0.y) R2X(aA0.z) R2X(aA0.w)
  R2X(aA1.x) R2X(aA1.y) R2X(aA1.z) R2X(aA1.w)
  R2X(aB0.x) R2X(aB0.y) R2X(aB0.z) R2X(aB0.w)
  R2X(aB1.x) R2X(aB1.y) R2X(aB1.z) R2X(aB1.w)
  #pragma unroll
  for (int off = 32; off >= 1; off >>= 1){
    Zp0  += __shfl_xor(Zp0,  off);  Zp1  += __shfl_xor(Zp1,  off);
    SWp0 += __shfl_xor(SWp0, off);  SWp1 += __shfl_xor(SWp1, off);
  }
  if (lane == 0){
    RL[h0]     = SWp0 / Zp0;
    RL[h0 + 1] = SWp1 / Zp1;
  }
  {
    const float invZ0 = 1.f/Zp0, invZ1 = 1.f/Zp1;
    if (q == 0){
      float4 v0 = aA0, v1 = aA1;
      v0.x*=invZ0; v0.y*=invZ0; v0.z*=invZ0; v0.w*=invZ0;
      v1.x*=invZ0; v1.y*=invZ0; v1.z*=invZ0; v1.w*=invZ0;
      *(float4*)&aggfin[h0*132 + 8*o]     = v0;
      *(float4*)&aggfin[h0*132 + 8*o + 4] = v1;
    } else if (q == 1){
      float4 v0 = aB0, v1 = aB1;
      v0.x*=invZ1; v0.y*=invZ1; v0.z*=invZ1; v0.w*=invZ1;
      v1.x*=invZ1; v1.y*=invZ1; v1.z*=invZ1; v1.w*=invZ1;
      *(float4*)&aggfin[(h0+1)*132 + 8*o]     = v0;
      *(float4*)&aggfin[(h0+1)*132 + 8*o + 4] = v1;
    }
  }
  __syncthreads();

  // cat[0:128] = project weighted sum through W1 head-slice; cat[128:256] = target_h
  if (t < 128){
    int h2 = t >> 4;
    float a = RL[h2] * b1[t];
    for (int d = 0; d < 128; ++d)
      a += aggfin[h2*132 + d] * W1[d*DD + t];
    catbuf[t]       = a;
    catbuf[128 + t] = targ[t];
  }
  __syncthreads();

  // out = cat @ W2 + b2 (2-way k-split)
  {
    int j = t & 127, kh = t >> 7;
    float o2 = 0.f;
    for (int k = kh*128; k < kh*128 + 128; ++k)
      o2 += catbuf[k] * W2[k*DD + j];
    oppart[t] = o2;
  }
  __syncthreads();
  if (t < 128)
    out[(long)blockIdx.x*128 + t] = oppart[t] + oppart[128 + t] + b2[t];
}

extern "C" void kernel_launch(void* const* d_in, const int* in_sizes, int n_in,
                              void* d_out, int out_size, void* d_ws, size_t ws_size,
                              hipStream_t stream) {
  const float* h    = (const float*)d_in[0];
  const float* adj  = (const float*)d_in[1];
  const float* mask = (const float*)d_in[2];
  const float* W1   = (const float*)d_in[3];
  const float* b1   = (const float*)d_in[4];
  const float* Wa   = (const float*)d_in[5];
  const float* ba   = (const float*)d_in[6];
  const float* W2   = (const float*)d_in[7];
  const float* b2   = (const float*)d_in[8];
  float* ws  = (float*)d_ws;
  float* out = (float*)d_out;

  gat_prep<<<4, 256, 0, stream>>>(W1, b1, Wa, ba, ws);
  gat_main<<<1024, 256, 0, stream>>>(h, adj, mask, W1, b1, W2, b2, ws, out);
}